// Round 1
// baseline (232.647 us; speedup 1.0000x reference)
//
#include <hip/hip_runtime.h>
#include <math.h>

#define NB   16
#define NH   512
#define NW   512
#define NM   64
#define NPTS 5
#define HW   (NH * NW)       // 262144
#define BHW  (NB * HW)       // 4194304

// ws float layout:
// [0]=bce_sum  [1]=inter_sum(p*t)  [2]=p_sum  [3]=t_sum
// [4]=sum(combined*valid)  [5]=sum(conf_per_sample*valid)  [6]=sum(valid)

__device__ __forceinline__ float wave_sum(float v) {
#pragma unroll
    for (int o = 32; o > 0; o >>= 1) v += __shfl_down(v, o, 64);
    return v;
}

// ---------------- Kernel 1: BCE + dice sums over the full maps ----------------
__global__ __launch_bounds__(256) void text_reduce_kernel(
        const float* __restrict__ p, const float* __restrict__ t,
        float* __restrict__ ws) {
    const float4* p4 = (const float4*)p;
    const float4* t4 = (const float4*)t;
    const int n4 = BHW / 4;
    float bce = 0.f, inter = 0.f, ps = 0.f, ts = 0.f;
    for (int i = blockIdx.x * blockDim.x + threadIdx.x; i < n4;
         i += gridDim.x * blockDim.x) {
        float4 pv = p4[i], tv = t4[i];
        {
            float pp = pv.x, tt = tv.x;
            bce -= tt * __logf(pp) + (1.f - tt) * __logf(1.f - pp);
            inter += pp * tt; ps += pp; ts += tt;
        }
        {
            float pp = pv.y, tt = tv.y;
            bce -= tt * __logf(pp) + (1.f - tt) * __logf(1.f - pp);
            inter += pp * tt; ps += pp; ts += tt;
        }
        {
            float pp = pv.z, tt = tv.z;
            bce -= tt * __logf(pp) + (1.f - tt) * __logf(1.f - pp);
            inter += pp * tt; ps += pp; ts += tt;
        }
        {
            float pp = pv.w, tt = tv.w;
            bce -= tt * __logf(pp) + (1.f - tt) * __logf(1.f - pp);
            inter += pp * tt; ps += pp; ts += tt;
        }
    }
    int lane = threadIdx.x & 63, wid = threadIdx.x >> 6;
    bce = wave_sum(bce); inter = wave_sum(inter);
    ps  = wave_sum(ps);  ts    = wave_sum(ts);
    __shared__ float sm[4][4];
    if (lane == 0) { sm[wid][0] = bce; sm[wid][1] = inter; sm[wid][2] = ps; sm[wid][3] = ts; }
    __syncthreads();
    if (threadIdx.x == 0) {
        float a = 0, b = 0, c = 0, d = 0;
#pragma unroll
        for (int i2 = 0; i2 < 4; i2++) { a += sm[i2][0]; b += sm[i2][1]; c += sm[i2][2]; d += sm[i2][3]; }
        atomicAdd(&ws[0], a); atomicAdd(&ws[1], b);
        atomicAdd(&ws[2], c); atomicAdd(&ws[3], d);
    }
}

// ---------------- Kernel 2: box + confidence loss, one block per batch ----------------
__global__ __launch_bounds__(320) void box_kernel(
        const float* __restrict__ confidence,   // [B,1,H,W]
        const float* __restrict__ bbox,         // [B,4,H,W]
        const float* __restrict__ tboxes,       // [B,M,5]
        const int*   __restrict__ bmask,        // [B,M]
        float* __restrict__ ws) {
    const int b   = blockIdx.x;
    const int tid = threadIdx.x;        // 0..319 = M*PTS points
    const int m   = tid / NPTS;
    const int j   = tid % NPTS;

    const float* tb = tboxes + (b * NM + m) * 5;
    float tconf = tb[0];
    // normalize + clip (exact: /512 == *2^-9)
    float nx1 = fminf(fmaxf(tb[1] * (1.0f / NW), 0.f), 1.f);
    float ny1 = fminf(fmaxf(tb[2] * (1.0f / NH), 0.f), 1.f);
    float nx2 = fminf(fmaxf(tb[3] * (1.0f / NW), 0.f), 1.f);
    float ny2 = fminf(fmaxf(tb[4] * (1.0f / NH), 0.f), 1.f);
    // pixel coords: astype(int32) truncates toward zero; values >= 0
    int x1p = min(max((int)(nx1 * (float)NW), 0), NW - 1);
    int y1p = min(max((int)(ny1 * (float)NH), 0), NH - 1);
    int x2p = min(max((int)(nx2 * (float)NW), 0), NW - 1);
    int y2p = min(max((int)(ny2 * (float)NH), 0), NH - 1);
    int cy = (y1p + y2p) >> 1;
    int cx = (x1p + x2p) >> 1;

    // ys = [cy, y1p, y1p, y2p, y2p]; xs = [cx, x1p, x2p, x1p, x2p]
    int yy, xx;
    switch (j) {
        case 0: yy = cy;  xx = cx;  break;
        case 1: yy = y1p; xx = x1p; break;
        case 2: yy = y1p; xx = x2p; break;
        case 3: yy = y2p; xx = x1p; break;
        default: yy = y2p; xx = x2p; break;
    }
    int off = yy * NW + xx;
    const float* bbp = bbox + (size_t)b * 4 * HW;
    float p0 = bbp[off];
    float p1 = bbp[HW + off];
    float p2 = bbp[2 * HW + off];
    float p3 = bbp[3 * HW + off];
    float cp = confidence[(size_t)b * HW + off];

    float px1 = fminf(fmaxf(p0, 0.00f), 0.99f);
    float py1 = fminf(fmaxf(p1, 0.00f), 0.99f);
    float px2 = fminf(fmaxf(p2, 0.01f), 1.00f);
    float py2 = fminf(fmaxf(p3, 0.01f), 1.00f);
    float cx1 = fminf(px1, px2), cx2 = fmaxf(px1, px2);
    float cy1 = fminf(py1, py2), cy2 = fmaxf(py1, py2);

    // iou / giou
    float pa = (cx2 - cx1) * (cy2 - cy1);
    float ta = (nx2 - nx1) * (ny2 - ny1);
    float ix1 = fmaxf(cx1, nx1), iy1 = fmaxf(cy1, ny1);
    float ix2 = fminf(cx2, nx2), iy2 = fminf(cy2, ny2);
    float inter = fmaxf(ix2 - ix1, 0.f) * fmaxf(iy2 - iy1, 0.f);
    float uni = pa + ta - inter;
    float iou = inter / (uni + 1e-6f);
    float ex1 = fminf(cx1, nx1), ey1 = fminf(cy1, ny1);
    float ex2 = fmaxf(cx2, nx2), ey2 = fmaxf(cy2, ny2);
    float enc = (ex2 - ex1) * (ey2 - ey1);
    float giou = iou - (enc - uni) / (enc + 1e-6f);

    float iou_pt  = -logf(iou + 1e-6f);
    float giou_pt = 1.f - giou;

    // smooth L1 over 4 coords
    float l1 = 0.f;
    {
        float d;
        d = fabsf(cx1 - nx1); l1 += (d < 1.f) ? 0.5f * d * d : d - 0.5f;
        d = fabsf(cy1 - ny1); l1 += (d < 1.f) ? 0.5f * d * d : d - 0.5f;
        d = fabsf(cx2 - nx2); l1 += (d < 1.f) ? 0.5f * d * d : d - 0.5f;
        d = fabsf(cy2 - ny2); l1 += (d < 1.f) ? 0.5f * d * d : d - 0.5f;
    }
    l1 *= 0.25f;

    // confidence BCE at the point
    float bcec = -(tconf * logf(cp) + (1.f - tconf) * logf(1.f - cp));

    float mk = (float)bmask[b * NM + m];

    float s_mask = mk;
    float s_iou  = iou_pt  * mk;
    float s_l1   = l1      * mk;
    float s_giou = giou_pt * mk;
    float s_conf = bcec    * mk;

    // block reduce over 320 threads (5 waves)
    int lane = tid & 63, wid = tid >> 6;
    s_mask = wave_sum(s_mask); s_iou = wave_sum(s_iou); s_l1 = wave_sum(s_l1);
    s_giou = wave_sum(s_giou); s_conf = wave_sum(s_conf);
    __shared__ float sm[5][5];
    if (lane == 0) {
        sm[wid][0] = s_mask; sm[wid][1] = s_iou; sm[wid][2] = s_l1;
        sm[wid][3] = s_giou; sm[wid][4] = s_conf;
    }
    __syncthreads();
    if (tid == 0) {
        float msum = 0, isum = 0, lsum = 0, gsum = 0, csum = 0;
#pragma unroll
        for (int w2 = 0; w2 < 5; w2++) {
            msum += sm[w2][0]; isum += sm[w2][1]; lsum += sm[w2][2];
            gsum += sm[w2][3]; csum += sm[w2][4];
        }
        float cnt = fmaxf(msum, 1.f);
        float combined = 0.5f * (isum / cnt) + 0.3f * (lsum / cnt) + 0.2f * (gsum / cnt);
        float conf_ps  = csum / cnt;
        float valid = (msum > 0.f) ? 1.f : 0.f;
        atomicAdd(&ws[4], combined * valid);
        atomicAdd(&ws[5], conf_ps * valid);
        atomicAdd(&ws[6], valid);
    }
}

// ---------------- Kernel 3: finalize ----------------
__global__ void finalize_kernel(const float* __restrict__ ws, float* __restrict__ out) {
    float bce_mean  = ws[0] / (float)BHW;
    float dice      = (2.f * ws[1] + 1e-5f) / (ws[2] + ws[3] + 1e-5f);
    float text_loss = 0.5f * bce_mean + 0.5f * (1.f - dice);
    float nvalid    = fmaxf(ws[6], 1.f);
    float box_loss  = ws[4] / nvalid;
    float conf_loss = ws[5] / nvalid;
    out[0] = 1.0f * text_loss + 20.0f * box_loss + 0.5f * conf_loss;
}

extern "C" void kernel_launch(void* const* d_in, const int* in_sizes, int n_in,
                              void* d_out, int out_size, void* d_ws, size_t ws_size,
                              hipStream_t stream) {
    const float* text_map        = (const float*)d_in[0];
    const float* confidence      = (const float*)d_in[1];
    const float* bbox_coords     = (const float*)d_in[2];
    const float* target_text_map = (const float*)d_in[3];
    const float* target_boxes    = (const float*)d_in[4];
    const int*   box_mask        = (const int*)d_in[5];
    float* out = (float*)d_out;
    float* ws  = (float*)d_ws;

    hipMemsetAsync(ws, 0, 8 * sizeof(float), stream);

    // 33.6 MB read; 2048 blocks x 256 thr, 2 float4 iterations/thread
    text_reduce_kernel<<<2048, 256, 0, stream>>>(text_map, target_text_map, ws);

    box_kernel<<<NB, NM * NPTS, 0, stream>>>(confidence, bbox_coords,
                                             target_boxes, box_mask, ws);

    finalize_kernel<<<1, 1, 0, stream>>>(ws, out);
}

// Round 2
// 132.865 us; speedup vs baseline: 1.7510x; 1.7510x over previous
//
#include <hip/hip_runtime.h>
#include <math.h>

#define NB   16
#define NH   512
#define NW   512
#define NM   64
#define NPTS 5
#define HW   (NH * NW)       // 262144
#define BHW  (NB * HW)       // 4194304

#define TR_BLOCKS 1024
#define TR_THREADS 256

// ws float layout:
// [0]=bce_sum  [1]=inter_sum(p*t)  [2]=p_sum  [3]=t_sum
// [4]=sum(combined*valid)  [5]=sum(conf_per_sample*valid)  [6]=sum(valid)
// [16..16+TR_BLOCKS*4) = per-block partials (float4 per block)

__device__ __forceinline__ float wave_sum(float v) {
#pragma unroll
    for (int o = 32; o > 0; o >>= 1) v += __shfl_down(v, o, 64);
    return v;
}

// ---------------- Kernel 1a: BCE + dice partial sums, NO atomics ----------------
__global__ __launch_bounds__(TR_THREADS) void text_partial_kernel(
        const float* __restrict__ p, const float* __restrict__ t,
        float4* __restrict__ partials) {
    const float4* p4 = (const float4*)p;
    const float4* t4 = (const float4*)t;
    const int base = blockIdx.x * TR_THREADS + threadIdx.x;
    const int stride = TR_BLOCKS * TR_THREADS;   // 262144; n4 = 1048576 -> 4 iters
    float bce = 0.f, inter = 0.f, ps = 0.f, ts = 0.f;
#pragma unroll
    for (int k = 0; k < 4; k++) {
        int i = base + k * stride;
        float4 pv = p4[i], tv = t4[i];
        {
            float pp = pv.x, tt = tv.x;
            bce -= tt * __logf(pp) + (1.f - tt) * __logf(1.f - pp);
            inter += pp * tt; ps += pp; ts += tt;
        }
        {
            float pp = pv.y, tt = tv.y;
            bce -= tt * __logf(pp) + (1.f - tt) * __logf(1.f - pp);
            inter += pp * tt; ps += pp; ts += tt;
        }
        {
            float pp = pv.z, tt = tv.z;
            bce -= tt * __logf(pp) + (1.f - tt) * __logf(1.f - pp);
            inter += pp * tt; ps += pp; ts += tt;
        }
        {
            float pp = pv.w, tt = tv.w;
            bce -= tt * __logf(pp) + (1.f - tt) * __logf(1.f - pp);
            inter += pp * tt; ps += pp; ts += tt;
        }
    }
    int lane = threadIdx.x & 63, wid = threadIdx.x >> 6;
    bce = wave_sum(bce); inter = wave_sum(inter);
    ps  = wave_sum(ps);  ts    = wave_sum(ts);
    __shared__ float sm[4][4];
    if (lane == 0) { sm[wid][0] = bce; sm[wid][1] = inter; sm[wid][2] = ps; sm[wid][3] = ts; }
    __syncthreads();
    if (threadIdx.x == 0) {
        float a = 0, b = 0, c = 0, d = 0;
#pragma unroll
        for (int i2 = 0; i2 < 4; i2++) { a += sm[i2][0]; b += sm[i2][1]; c += sm[i2][2]; d += sm[i2][3]; }
        partials[blockIdx.x] = make_float4(a, b, c, d);
    }
}

// ---------------- Kernel 1b: reduce the 1024 partials ----------------
__global__ __launch_bounds__(256) void text_final_kernel(
        const float4* __restrict__ partials, float* __restrict__ ws) {
    float a = 0.f, b = 0.f, c = 0.f, d = 0.f;
#pragma unroll
    for (int k = 0; k < TR_BLOCKS / 256; k++) {
        float4 v = partials[threadIdx.x + k * 256];
        a += v.x; b += v.y; c += v.z; d += v.w;
    }
    int lane = threadIdx.x & 63, wid = threadIdx.x >> 6;
    a = wave_sum(a); b = wave_sum(b); c = wave_sum(c); d = wave_sum(d);
    __shared__ float sm[4][4];
    if (lane == 0) { sm[wid][0] = a; sm[wid][1] = b; sm[wid][2] = c; sm[wid][3] = d; }
    __syncthreads();
    if (threadIdx.x == 0) {
        float s0 = 0, s1 = 0, s2 = 0, s3 = 0;
#pragma unroll
        for (int i2 = 0; i2 < 4; i2++) { s0 += sm[i2][0]; s1 += sm[i2][1]; s2 += sm[i2][2]; s3 += sm[i2][3]; }
        ws[0] = s0; ws[1] = s1; ws[2] = s2; ws[3] = s3;
    }
}

// ---------------- Kernel 2: box + confidence loss, one block per batch ----------------
__global__ __launch_bounds__(320) void box_kernel(
        const float* __restrict__ confidence,   // [B,1,H,W]
        const float* __restrict__ bbox,         // [B,4,H,W]
        const float* __restrict__ tboxes,       // [B,M,5]
        const int*   __restrict__ bmask,        // [B,M]
        float* __restrict__ ws) {
    const int b   = blockIdx.x;
    const int tid = threadIdx.x;        // 0..319 = M*PTS points
    const int m   = tid / NPTS;
    const int j   = tid % NPTS;

    const float* tb = tboxes + (b * NM + m) * 5;
    float tconf = tb[0];
    float nx1 = fminf(fmaxf(tb[1] * (1.0f / NW), 0.f), 1.f);
    float ny1 = fminf(fmaxf(tb[2] * (1.0f / NH), 0.f), 1.f);
    float nx2 = fminf(fmaxf(tb[3] * (1.0f / NW), 0.f), 1.f);
    float ny2 = fminf(fmaxf(tb[4] * (1.0f / NH), 0.f), 1.f);
    int x1p = min(max((int)(nx1 * (float)NW), 0), NW - 1);
    int y1p = min(max((int)(ny1 * (float)NH), 0), NH - 1);
    int x2p = min(max((int)(nx2 * (float)NW), 0), NW - 1);
    int y2p = min(max((int)(ny2 * (float)NH), 0), NH - 1);
    int cy = (y1p + y2p) >> 1;
    int cx = (x1p + x2p) >> 1;

    int yy, xx;
    switch (j) {
        case 0: yy = cy;  xx = cx;  break;
        case 1: yy = y1p; xx = x1p; break;
        case 2: yy = y1p; xx = x2p; break;
        case 3: yy = y2p; xx = x1p; break;
        default: yy = y2p; xx = x2p; break;
    }
    int off = yy * NW + xx;
    const float* bbp = bbox + (size_t)b * 4 * HW;
    float p0 = bbp[off];
    float p1 = bbp[HW + off];
    float p2 = bbp[2 * HW + off];
    float p3 = bbp[3 * HW + off];
    float cp = confidence[(size_t)b * HW + off];

    float px1 = fminf(fmaxf(p0, 0.00f), 0.99f);
    float py1 = fminf(fmaxf(p1, 0.00f), 0.99f);
    float px2 = fminf(fmaxf(p2, 0.01f), 1.00f);
    float py2 = fminf(fmaxf(p3, 0.01f), 1.00f);
    float cx1 = fminf(px1, px2), cx2 = fmaxf(px1, px2);
    float cy1 = fminf(py1, py2), cy2 = fmaxf(py1, py2);

    float pa = (cx2 - cx1) * (cy2 - cy1);
    float ta = (nx2 - nx1) * (ny2 - ny1);
    float ix1 = fmaxf(cx1, nx1), iy1 = fmaxf(cy1, ny1);
    float ix2 = fminf(cx2, nx2), iy2 = fminf(cy2, ny2);
    float inter = fmaxf(ix2 - ix1, 0.f) * fmaxf(iy2 - iy1, 0.f);
    float uni = pa + ta - inter;
    float iou = inter / (uni + 1e-6f);
    float ex1 = fminf(cx1, nx1), ey1 = fminf(cy1, ny1);
    float ex2 = fmaxf(cx2, nx2), ey2 = fmaxf(cy2, ny2);
    float enc = (ex2 - ex1) * (ey2 - ey1);
    float giou = iou - (enc - uni) / (enc + 1e-6f);

    float iou_pt  = -logf(iou + 1e-6f);
    float giou_pt = 1.f - giou;

    float l1 = 0.f;
    {
        float d;
        d = fabsf(cx1 - nx1); l1 += (d < 1.f) ? 0.5f * d * d : d - 0.5f;
        d = fabsf(cy1 - ny1); l1 += (d < 1.f) ? 0.5f * d * d : d - 0.5f;
        d = fabsf(cx2 - nx2); l1 += (d < 1.f) ? 0.5f * d * d : d - 0.5f;
        d = fabsf(cy2 - ny2); l1 += (d < 1.f) ? 0.5f * d * d : d - 0.5f;
    }
    l1 *= 0.25f;

    float bcec = -(tconf * logf(cp) + (1.f - tconf) * logf(1.f - cp));

    float mk = (float)bmask[b * NM + m];

    float s_mask = mk;
    float s_iou  = iou_pt  * mk;
    float s_l1   = l1      * mk;
    float s_giou = giou_pt * mk;
    float s_conf = bcec    * mk;

    int lane = tid & 63, wid = tid >> 6;
    s_mask = wave_sum(s_mask); s_iou = wave_sum(s_iou); s_l1 = wave_sum(s_l1);
    s_giou = wave_sum(s_giou); s_conf = wave_sum(s_conf);
    __shared__ float sm[5][5];
    if (lane == 0) {
        sm[wid][0] = s_mask; sm[wid][1] = s_iou; sm[wid][2] = s_l1;
        sm[wid][3] = s_giou; sm[wid][4] = s_conf;
    }
    __syncthreads();
    if (tid == 0) {
        float msum = 0, isum = 0, lsum = 0, gsum = 0, csum = 0;
#pragma unroll
        for (int w2 = 0; w2 < 5; w2++) {
            msum += sm[w2][0]; isum += sm[w2][1]; lsum += sm[w2][2];
            gsum += sm[w2][3]; csum += sm[w2][4];
        }
        float cnt = fmaxf(msum, 1.f);
        float combined = 0.5f * (isum / cnt) + 0.3f * (lsum / cnt) + 0.2f * (gsum / cnt);
        float conf_ps  = csum / cnt;
        float valid = (msum > 0.f) ? 1.f : 0.f;
        atomicAdd(&ws[4], combined * valid);
        atomicAdd(&ws[5], conf_ps * valid);
        atomicAdd(&ws[6], valid);
    }
}

// ---------------- Kernel 3: finalize ----------------
__global__ void finalize_kernel(const float* __restrict__ ws, float* __restrict__ out) {
    float bce_mean  = ws[0] / (float)BHW;
    float dice      = (2.f * ws[1] + 1e-5f) / (ws[2] + ws[3] + 1e-5f);
    float text_loss = 0.5f * bce_mean + 0.5f * (1.f - dice);
    float nvalid    = fmaxf(ws[6], 1.f);
    float box_loss  = ws[4] / nvalid;
    float conf_loss = ws[5] / nvalid;
    out[0] = 1.0f * text_loss + 20.0f * box_loss + 0.5f * conf_loss;
}

extern "C" void kernel_launch(void* const* d_in, const int* in_sizes, int n_in,
                              void* d_out, int out_size, void* d_ws, size_t ws_size,
                              hipStream_t stream) {
    const float* text_map        = (const float*)d_in[0];
    const float* confidence      = (const float*)d_in[1];
    const float* bbox_coords     = (const float*)d_in[2];
    const float* target_text_map = (const float*)d_in[3];
    const float* target_boxes    = (const float*)d_in[4];
    const int*   box_mask        = (const int*)d_in[5];
    float* out = (float*)d_out;
    float* ws  = (float*)d_ws;

    float4* partials = (float4*)((char*)d_ws + 64);   // 1024 * 16 B = 16 KiB

    // zero the accumulator head (box_kernel atomics need zeros)
    hipMemsetAsync(ws, 0, 8 * sizeof(float), stream);

    // 33.6 MB read; no atomics — per-block partials
    text_partial_kernel<<<TR_BLOCKS, TR_THREADS, 0, stream>>>(
        text_map, target_text_map, partials);
    text_final_kernel<<<1, 256, 0, stream>>>(partials, ws);

    box_kernel<<<NB, NM * NPTS, 0, stream>>>(confidence, bbox_coords,
                                             target_boxes, box_mask, ws);

    finalize_kernel<<<1, 1, 0, stream>>>(ws, out);
}

// Round 3
// 130.362 us; speedup vs baseline: 1.7846x; 1.0192x over previous
//
#include <hip/hip_runtime.h>
#include <math.h>

#define NB   16
#define NH   512
#define NW   512
#define NM   64
#define NPTS 5
#define HW   (NH * NW)       // 262144
#define BHW  (NB * HW)       // 4194304

#define TR_BLOCKS 1024
#define TR_THREADS 256

// ws float layout (no zero-init required — every slot is written before read):
// [0..15]   = per-batch combined*valid
// [16..31]  = per-batch conf_per_sample*valid
// [32..47]  = per-batch valid
// byte offset 256 onward: TR_BLOCKS float4 text partials (16 KiB)

__device__ __forceinline__ float wave_sum(float v) {
#pragma unroll
    for (int o = 32; o > 0; o >>= 1) v += __shfl_down(v, o, 64);
    return v;
}

// ---------------- Kernel 1: BCE + dice partial sums, no atomics ----------------
__global__ __launch_bounds__(TR_THREADS) void text_partial_kernel(
        const float* __restrict__ p, const float* __restrict__ t,
        float4* __restrict__ partials) {
    const float4* p4 = (const float4*)p;
    const float4* t4 = (const float4*)t;
    const int base = blockIdx.x * TR_THREADS + threadIdx.x;
    const int stride = TR_BLOCKS * TR_THREADS;   // 262144; n4 = 1048576 -> 4 iters
    float bce = 0.f, inter = 0.f, ps = 0.f, ts = 0.f;
#pragma unroll
    for (int k = 0; k < 4; k++) {
        int i = base + k * stride;
        float4 pv = p4[i], tv = t4[i];
        {
            float pp = pv.x, tt = tv.x;
            bce -= tt * __logf(pp) + (1.f - tt) * __logf(1.f - pp);
            inter += pp * tt; ps += pp; ts += tt;
        }
        {
            float pp = pv.y, tt = tv.y;
            bce -= tt * __logf(pp) + (1.f - tt) * __logf(1.f - pp);
            inter += pp * tt; ps += pp; ts += tt;
        }
        {
            float pp = pv.z, tt = tv.z;
            bce -= tt * __logf(pp) + (1.f - tt) * __logf(1.f - pp);
            inter += pp * tt; ps += pp; ts += tt;
        }
        {
            float pp = pv.w, tt = tv.w;
            bce -= tt * __logf(pp) + (1.f - tt) * __logf(1.f - pp);
            inter += pp * tt; ps += pp; ts += tt;
        }
    }
    int lane = threadIdx.x & 63, wid = threadIdx.x >> 6;
    bce = wave_sum(bce); inter = wave_sum(inter);
    ps  = wave_sum(ps);  ts    = wave_sum(ts);
    __shared__ float sm[4][4];
    if (lane == 0) { sm[wid][0] = bce; sm[wid][1] = inter; sm[wid][2] = ps; sm[wid][3] = ts; }
    __syncthreads();
    if (threadIdx.x == 0) {
        float a = 0, b = 0, c = 0, d = 0;
#pragma unroll
        for (int i2 = 0; i2 < 4; i2++) { a += sm[i2][0]; b += sm[i2][1]; c += sm[i2][2]; d += sm[i2][3]; }
        partials[blockIdx.x] = make_float4(a, b, c, d);
    }
}

// ---------------- Kernel 2: box + confidence, one block per batch, no atomics ----------------
__global__ __launch_bounds__(320) void box_kernel(
        const float* __restrict__ confidence,   // [B,1,H,W]
        const float* __restrict__ bbox,         // [B,4,H,W]
        const float* __restrict__ tboxes,       // [B,M,5]
        const int*   __restrict__ bmask,        // [B,M]
        float* __restrict__ ws) {
    const int b   = blockIdx.x;
    const int tid = threadIdx.x;        // 0..319 = M*PTS points
    const int m   = tid / NPTS;
    const int j   = tid % NPTS;

    const float* tb = tboxes + (b * NM + m) * 5;
    float tconf = tb[0];
    float nx1 = fminf(fmaxf(tb[1] * (1.0f / NW), 0.f), 1.f);
    float ny1 = fminf(fmaxf(tb[2] * (1.0f / NH), 0.f), 1.f);
    float nx2 = fminf(fmaxf(tb[3] * (1.0f / NW), 0.f), 1.f);
    float ny2 = fminf(fmaxf(tb[4] * (1.0f / NH), 0.f), 1.f);
    int x1p = min(max((int)(nx1 * (float)NW), 0), NW - 1);
    int y1p = min(max((int)(ny1 * (float)NH), 0), NH - 1);
    int x2p = min(max((int)(nx2 * (float)NW), 0), NW - 1);
    int y2p = min(max((int)(ny2 * (float)NH), 0), NH - 1);
    int cy = (y1p + y2p) >> 1;
    int cx = (x1p + x2p) >> 1;

    int yy, xx;
    switch (j) {
        case 0: yy = cy;  xx = cx;  break;
        case 1: yy = y1p; xx = x1p; break;
        case 2: yy = y1p; xx = x2p; break;
        case 3: yy = y2p; xx = x1p; break;
        default: yy = y2p; xx = x2p; break;
    }
    int off = yy * NW + xx;
    const float* bbp = bbox + (size_t)b * 4 * HW;
    float p0 = bbp[off];
    float p1 = bbp[HW + off];
    float p2 = bbp[2 * HW + off];
    float p3 = bbp[3 * HW + off];
    float cp = confidence[(size_t)b * HW + off];

    float px1 = fminf(fmaxf(p0, 0.00f), 0.99f);
    float py1 = fminf(fmaxf(p1, 0.00f), 0.99f);
    float px2 = fminf(fmaxf(p2, 0.01f), 1.00f);
    float py2 = fminf(fmaxf(p3, 0.01f), 1.00f);
    float cx1 = fminf(px1, px2), cx2 = fmaxf(px1, px2);
    float cy1 = fminf(py1, py2), cy2 = fmaxf(py1, py2);

    float pa = (cx2 - cx1) * (cy2 - cy1);
    float ta = (nx2 - nx1) * (ny2 - ny1);
    float ix1 = fmaxf(cx1, nx1), iy1 = fmaxf(cy1, ny1);
    float ix2 = fminf(cx2, nx2), iy2 = fminf(cy2, ny2);
    float inter = fmaxf(ix2 - ix1, 0.f) * fmaxf(iy2 - iy1, 0.f);
    float uni = pa + ta - inter;
    float iou = inter / (uni + 1e-6f);
    float ex1 = fminf(cx1, nx1), ey1 = fminf(cy1, ny1);
    float ex2 = fmaxf(cx2, nx2), ey2 = fmaxf(cy2, ny2);
    float enc = (ex2 - ex1) * (ey2 - ey1);
    float giou = iou - (enc - uni) / (enc + 1e-6f);

    float iou_pt  = -logf(iou + 1e-6f);
    float giou_pt = 1.f - giou;

    float l1 = 0.f;
    {
        float d;
        d = fabsf(cx1 - nx1); l1 += (d < 1.f) ? 0.5f * d * d : d - 0.5f;
        d = fabsf(cy1 - ny1); l1 += (d < 1.f) ? 0.5f * d * d : d - 0.5f;
        d = fabsf(cx2 - nx2); l1 += (d < 1.f) ? 0.5f * d * d : d - 0.5f;
        d = fabsf(cy2 - ny2); l1 += (d < 1.f) ? 0.5f * d * d : d - 0.5f;
    }
    l1 *= 0.25f;

    float bcec = -(tconf * logf(cp) + (1.f - tconf) * logf(1.f - cp));

    float mk = (float)bmask[b * NM + m];

    float s_mask = mk;
    float s_iou  = iou_pt  * mk;
    float s_l1   = l1      * mk;
    float s_giou = giou_pt * mk;
    float s_conf = bcec    * mk;

    int lane = tid & 63, wid = tid >> 6;
    s_mask = wave_sum(s_mask); s_iou = wave_sum(s_iou); s_l1 = wave_sum(s_l1);
    s_giou = wave_sum(s_giou); s_conf = wave_sum(s_conf);
    __shared__ float sm[5][5];
    if (lane == 0) {
        sm[wid][0] = s_mask; sm[wid][1] = s_iou; sm[wid][2] = s_l1;
        sm[wid][3] = s_giou; sm[wid][4] = s_conf;
    }
    __syncthreads();
    if (tid == 0) {
        float msum = 0, isum = 0, lsum = 0, gsum = 0, csum = 0;
#pragma unroll
        for (int w2 = 0; w2 < 5; w2++) {
            msum += sm[w2][0]; isum += sm[w2][1]; lsum += sm[w2][2];
            gsum += sm[w2][3]; csum += sm[w2][4];
        }
        float cnt = fmaxf(msum, 1.f);
        float combined = 0.5f * (isum / cnt) + 0.3f * (lsum / cnt) + 0.2f * (gsum / cnt);
        float conf_ps  = csum / cnt;
        float valid = (msum > 0.f) ? 1.f : 0.f;
        ws[b]          = combined * valid;   // distinct slots — no atomics
        ws[16 + b]     = conf_ps * valid;
        ws[32 + b]     = valid;
    }
}

// ---------------- Kernel 3: fused final reduce + output ----------------
__global__ __launch_bounds__(256) void final_kernel(
        const float4* __restrict__ partials, const float* __restrict__ ws,
        float* __restrict__ out) {
    float a = 0.f, b = 0.f, c = 0.f, d = 0.f;
#pragma unroll
    for (int k = 0; k < TR_BLOCKS / 256; k++) {
        float4 v = partials[threadIdx.x + k * 256];
        a += v.x; b += v.y; c += v.z; d += v.w;
    }
    int lane = threadIdx.x & 63, wid = threadIdx.x >> 6;
    a = wave_sum(a); b = wave_sum(b); c = wave_sum(c); d = wave_sum(d);
    __shared__ float sm[4][4];
    if (lane == 0) { sm[wid][0] = a; sm[wid][1] = b; sm[wid][2] = c; sm[wid][3] = d; }
    __syncthreads();
    if (threadIdx.x == 0) {
        float s0 = 0, s1 = 0, s2 = 0, s3 = 0;
#pragma unroll
        for (int i2 = 0; i2 < 4; i2++) { s0 += sm[i2][0]; s1 += sm[i2][1]; s2 += sm[i2][2]; s3 += sm[i2][3]; }
        // text loss
        float bce_mean  = s0 / (float)BHW;
        float dice      = (2.f * s1 + 1e-5f) / (s2 + s3 + 1e-5f);
        float text_loss = 0.5f * bce_mean + 0.5f * (1.f - dice);
        // box + conf loss from per-batch triples
        float box_sum = 0.f, conf_sum = 0.f, valid_sum = 0.f;
#pragma unroll
        for (int bb = 0; bb < NB; bb++) {
            box_sum   += ws[bb];
            conf_sum  += ws[16 + bb];
            valid_sum += ws[32 + bb];
        }
        float nvalid = fmaxf(valid_sum, 1.f);
        out[0] = 1.0f * text_loss + 20.0f * (box_sum / nvalid) + 0.5f * (conf_sum / nvalid);
    }
}

extern "C" void kernel_launch(void* const* d_in, const int* in_sizes, int n_in,
                              void* d_out, int out_size, void* d_ws, size_t ws_size,
                              hipStream_t stream) {
    const float* text_map        = (const float*)d_in[0];
    const float* confidence      = (const float*)d_in[1];
    const float* bbox_coords     = (const float*)d_in[2];
    const float* target_text_map = (const float*)d_in[3];
    const float* target_boxes    = (const float*)d_in[4];
    const int*   box_mask        = (const int*)d_in[5];
    float* out = (float*)d_out;
    float* ws  = (float*)d_ws;

    float4* partials = (float4*)((char*)d_ws + 256);   // 1024 * 16 B = 16 KiB

    // 33.6 MB read; per-block partials, no atomics, no memset
    text_partial_kernel<<<TR_BLOCKS, TR_THREADS, 0, stream>>>(
        text_map, target_text_map, partials);

    box_kernel<<<NB, NM * NPTS, 0, stream>>>(confidence, bbox_coords,
                                             target_boxes, box_mask, ws);

    final_kernel<<<1, 256, 0, stream>>>(partials, ws, out);
}

// Round 4
// 127.447 us; speedup vs baseline: 1.8254x; 1.0229x over previous
//
#include <hip/hip_runtime.h>
#include <math.h>

#define NB   16
#define NH   512
#define NW   512
#define NM   64
#define NPTS 5
#define HW   (NH * NW)       // 262144
#define BHW  (NB * HW)       // 4194304

#define TR_BLOCKS 1024
#define THREADS   320        // 5 waves; box needs 320, text uses bounds-checked loop

// ws float layout (no zero-init required — every slot written before read):
// [0..15]  = per-batch combined*valid
// [16..31] = per-batch conf_per_sample*valid
// [32..47] = per-batch valid
// byte offset 256 onward: TR_BLOCKS float4 text partials (16 KiB)

__device__ __forceinline__ float wave_sum(float v) {
#pragma unroll
    for (int o = 32; o > 0; o >>= 1) v += __shfl_down(v, o, 64);
    return v;
}

// ---------------- Kernel 1: fused text partials + box/conf, heterogeneous grid ----------------
__global__ __launch_bounds__(THREADS) void fused_main_kernel(
        const float* __restrict__ p, const float* __restrict__ t,
        const float* __restrict__ confidence,   // [B,1,H,W]
        const float* __restrict__ bbox,         // [B,4,H,W]
        const float* __restrict__ tboxes,       // [B,M,5]
        const int*   __restrict__ bmask,        // [B,M]
        float4* __restrict__ partials,
        float* __restrict__ ws) {
    __shared__ float sm[5][5];
    const int tid  = threadIdx.x;
    const int lane = tid & 63, wid = tid >> 6;

    if (blockIdx.x < TR_BLOCKS) {
        // ---- text BCE + dice partial sums ----
        const float4* p4 = (const float4*)p;
        const float4* t4 = (const float4*)t;
        const int n4     = BHW / 4;              // 1048576
        const int base   = blockIdx.x * THREADS + tid;
        const int stride = TR_BLOCKS * THREADS;  // 327680
        float bce = 0.f, inter = 0.f, ps = 0.f, ts = 0.f;
#pragma unroll
        for (int k = 0; k < 4; k++) {
            int i = base + k * stride;           // only k==3 can go OOB
            if (i < n4) {
                float4 pv = p4[i], tv = t4[i];
                {
                    float pp = pv.x, tt = tv.x;
                    bce -= tt * __logf(pp) + (1.f - tt) * __logf(1.f - pp);
                    inter += pp * tt; ps += pp; ts += tt;
                }
                {
                    float pp = pv.y, tt = tv.y;
                    bce -= tt * __logf(pp) + (1.f - tt) * __logf(1.f - pp);
                    inter += pp * tt; ps += pp; ts += tt;
                }
                {
                    float pp = pv.z, tt = tv.z;
                    bce -= tt * __logf(pp) + (1.f - tt) * __logf(1.f - pp);
                    inter += pp * tt; ps += pp; ts += tt;
                }
                {
                    float pp = pv.w, tt = tv.w;
                    bce -= tt * __logf(pp) + (1.f - tt) * __logf(1.f - pp);
                    inter += pp * tt; ps += pp; ts += tt;
                }
            }
        }
        bce = wave_sum(bce); inter = wave_sum(inter);
        ps  = wave_sum(ps);  ts    = wave_sum(ts);
        if (lane == 0) { sm[wid][0] = bce; sm[wid][1] = inter; sm[wid][2] = ps; sm[wid][3] = ts; }
        __syncthreads();
        if (tid == 0) {
            float a = 0, b = 0, c = 0, d = 0;
#pragma unroll
            for (int i2 = 0; i2 < 5; i2++) { a += sm[i2][0]; b += sm[i2][1]; c += sm[i2][2]; d += sm[i2][3]; }
            partials[blockIdx.x] = make_float4(a, b, c, d);
        }
    } else {
        // ---- box + confidence loss, one block per batch ----
        const int b = blockIdx.x - TR_BLOCKS;
        const int m = tid / NPTS;
        const int j = tid % NPTS;

        const float* tb = tboxes + (b * NM + m) * 5;
        float tconf = tb[0];
        float nx1 = fminf(fmaxf(tb[1] * (1.0f / NW), 0.f), 1.f);
        float ny1 = fminf(fmaxf(tb[2] * (1.0f / NH), 0.f), 1.f);
        float nx2 = fminf(fmaxf(tb[3] * (1.0f / NW), 0.f), 1.f);
        float ny2 = fminf(fmaxf(tb[4] * (1.0f / NH), 0.f), 1.f);
        int x1p = min(max((int)(nx1 * (float)NW), 0), NW - 1);
        int y1p = min(max((int)(ny1 * (float)NH), 0), NH - 1);
        int x2p = min(max((int)(nx2 * (float)NW), 0), NW - 1);
        int y2p = min(max((int)(ny2 * (float)NH), 0), NH - 1);
        int cy = (y1p + y2p) >> 1;
        int cx = (x1p + x2p) >> 1;

        int yy, xx;
        switch (j) {
            case 0: yy = cy;  xx = cx;  break;
            case 1: yy = y1p; xx = x1p; break;
            case 2: yy = y1p; xx = x2p; break;
            case 3: yy = y2p; xx = x1p; break;
            default: yy = y2p; xx = x2p; break;
        }
        int off = yy * NW + xx;
        const float* bbp = bbox + (size_t)b * 4 * HW;
        float p0 = bbp[off];
        float p1 = bbp[HW + off];
        float p2 = bbp[2 * HW + off];
        float p3 = bbp[3 * HW + off];
        float cp = confidence[(size_t)b * HW + off];

        float px1 = fminf(fmaxf(p0, 0.00f), 0.99f);
        float py1 = fminf(fmaxf(p1, 0.00f), 0.99f);
        float px2 = fminf(fmaxf(p2, 0.01f), 1.00f);
        float py2 = fminf(fmaxf(p3, 0.01f), 1.00f);
        float cx1 = fminf(px1, px2), cx2 = fmaxf(px1, px2);
        float cy1 = fminf(py1, py2), cy2 = fmaxf(py1, py2);

        float pa = (cx2 - cx1) * (cy2 - cy1);
        float ta = (nx2 - nx1) * (ny2 - ny1);
        float ix1 = fmaxf(cx1, nx1), iy1 = fmaxf(cy1, ny1);
        float ix2 = fminf(cx2, nx2), iy2 = fminf(cy2, ny2);
        float inter = fmaxf(ix2 - ix1, 0.f) * fmaxf(iy2 - iy1, 0.f);
        float uni = pa + ta - inter;
        float iou = inter / (uni + 1e-6f);
        float ex1 = fminf(cx1, nx1), ey1 = fminf(cy1, ny1);
        float ex2 = fmaxf(cx2, nx2), ey2 = fmaxf(cy2, ny2);
        float enc = (ex2 - ex1) * (ey2 - ey1);
        float giou = iou - (enc - uni) / (enc + 1e-6f);

        float iou_pt  = -logf(iou + 1e-6f);
        float giou_pt = 1.f - giou;

        float l1 = 0.f;
        {
            float d;
            d = fabsf(cx1 - nx1); l1 += (d < 1.f) ? 0.5f * d * d : d - 0.5f;
            d = fabsf(cy1 - ny1); l1 += (d < 1.f) ? 0.5f * d * d : d - 0.5f;
            d = fabsf(cx2 - nx2); l1 += (d < 1.f) ? 0.5f * d * d : d - 0.5f;
            d = fabsf(cy2 - ny2); l1 += (d < 1.f) ? 0.5f * d * d : d - 0.5f;
        }
        l1 *= 0.25f;

        float bcec = -(tconf * logf(cp) + (1.f - tconf) * logf(1.f - cp));

        float mk = (float)bmask[b * NM + m];

        float s_mask = mk;
        float s_iou  = iou_pt  * mk;
        float s_l1   = l1      * mk;
        float s_giou = giou_pt * mk;
        float s_conf = bcec    * mk;

        s_mask = wave_sum(s_mask); s_iou = wave_sum(s_iou); s_l1 = wave_sum(s_l1);
        s_giou = wave_sum(s_giou); s_conf = wave_sum(s_conf);
        if (lane == 0) {
            sm[wid][0] = s_mask; sm[wid][1] = s_iou; sm[wid][2] = s_l1;
            sm[wid][3] = s_giou; sm[wid][4] = s_conf;
        }
        __syncthreads();
        if (tid == 0) {
            float msum = 0, isum = 0, lsum = 0, gsum = 0, csum = 0;
#pragma unroll
            for (int w2 = 0; w2 < 5; w2++) {
                msum += sm[w2][0]; isum += sm[w2][1]; lsum += sm[w2][2];
                gsum += sm[w2][3]; csum += sm[w2][4];
            }
            float cnt = fmaxf(msum, 1.f);
            float combined = 0.5f * (isum / cnt) + 0.3f * (lsum / cnt) + 0.2f * (gsum / cnt);
            float conf_ps  = csum / cnt;
            float valid = (msum > 0.f) ? 1.f : 0.f;
            ws[b]      = combined * valid;   // distinct slots — no atomics
            ws[16 + b] = conf_ps * valid;
            ws[32 + b] = valid;
        }
    }
}

// ---------------- Kernel 2: fused final reduce + output ----------------
__global__ __launch_bounds__(256) void final_kernel(
        const float4* __restrict__ partials, const float* __restrict__ ws,
        float* __restrict__ out) {
    float a = 0.f, b = 0.f, c = 0.f, d = 0.f;
#pragma unroll
    for (int k = 0; k < TR_BLOCKS / 256; k++) {
        float4 v = partials[threadIdx.x + k * 256];
        a += v.x; b += v.y; c += v.z; d += v.w;
    }
    int lane = threadIdx.x & 63, wid = threadIdx.x >> 6;
    a = wave_sum(a); b = wave_sum(b); c = wave_sum(c); d = wave_sum(d);
    __shared__ float sm[4][4];
    if (lane == 0) { sm[wid][0] = a; sm[wid][1] = b; sm[wid][2] = c; sm[wid][3] = d; }
    __syncthreads();
    if (threadIdx.x == 0) {
        float s0 = 0, s1 = 0, s2 = 0, s3 = 0;
#pragma unroll
        for (int i2 = 0; i2 < 4; i2++) { s0 += sm[i2][0]; s1 += sm[i2][1]; s2 += sm[i2][2]; s3 += sm[i2][3]; }
        float bce_mean  = s0 / (float)BHW;
        float dice      = (2.f * s1 + 1e-5f) / (s2 + s3 + 1e-5f);
        float text_loss = 0.5f * bce_mean + 0.5f * (1.f - dice);
        float box_sum = 0.f, conf_sum = 0.f, valid_sum = 0.f;
#pragma unroll
        for (int bb = 0; bb < NB; bb++) {
            box_sum   += ws[bb];
            conf_sum  += ws[16 + bb];
            valid_sum += ws[32 + bb];
        }
        float nvalid = fmaxf(valid_sum, 1.f);
        out[0] = 1.0f * text_loss + 20.0f * (box_sum / nvalid) + 0.5f * (conf_sum / nvalid);
    }
}

extern "C" void kernel_launch(void* const* d_in, const int* in_sizes, int n_in,
                              void* d_out, int out_size, void* d_ws, size_t ws_size,
                              hipStream_t stream) {
    const float* text_map        = (const float*)d_in[0];
    const float* confidence      = (const float*)d_in[1];
    const float* bbox_coords     = (const float*)d_in[2];
    const float* target_text_map = (const float*)d_in[3];
    const float* target_boxes    = (const float*)d_in[4];
    const int*   box_mask        = (const int*)d_in[5];
    float* out = (float*)d_out;
    float* ws  = (float*)d_ws;

    float4* partials = (float4*)((char*)d_ws + 256);   // 1024 * 16 B = 16 KiB

    // Blocks 0..1023: text partials (33.6 MB read). Blocks 1024..1039: box/conf.
    fused_main_kernel<<<TR_BLOCKS + NB, THREADS, 0, stream>>>(
        text_map, target_text_map, confidence, bbox_coords,
        target_boxes, box_mask, partials, ws);

    final_kernel<<<1, 256, 0, stream>>>(partials, ws, out);
}

// Round 6
// 125.891 us; speedup vs baseline: 1.8480x; 1.0124x over previous
//
#include <hip/hip_runtime.h>
#include <math.h>

#define NB   16
#define NH   512
#define NW   512
#define NM   64
#define NPTS 5
#define HW   (NH * NW)       // 262144
#define BHW  (NB * HW)       // 4194304

#define TR_BLOCKS 1024
#define THREADS   320        // 5 waves; box needs 320, text uses bounds-checked loop

// ws float layout (no zero-init required — every slot written before read):
// [0..15]  = per-batch combined*valid
// [16..31] = per-batch conf_per_sample*valid
// [32..47] = per-batch valid
// byte offset 256 onward: TR_BLOCKS float4 text partials (16 KiB)

__device__ __forceinline__ float wave_sum(float v) {
#pragma unroll
    for (int o = 32; o > 0; o >>= 1) v += __shfl_down(v, o, 64);
    return v;
}

// ---------------- Kernel 1: fused text partials + box/conf, heterogeneous grid ----------------
__global__ __launch_bounds__(THREADS) void fused_main_kernel(
        const float* __restrict__ p, const float* __restrict__ t,
        const float* __restrict__ confidence,   // [B,1,H,W]
        const float* __restrict__ bbox,         // [B,4,H,W]
        const float* __restrict__ tboxes,       // [B,M,5]
        const int*   __restrict__ bmask,        // [B,M]
        float4* __restrict__ partials,
        float* __restrict__ ws) {
    __shared__ float sm[5][5];
    const int tid  = threadIdx.x;
    const int lane = tid & 63, wid = tid >> 6;

    if (blockIdx.x < TR_BLOCKS) {
        // ---- text BCE + dice partial sums ----
        const float4* p4 = (const float4*)p;
        const float4* t4 = (const float4*)t;
        const int n4     = BHW / 4;              // 1048576
        const int base   = blockIdx.x * THREADS + tid;
        const int stride = TR_BLOCKS * THREADS;  // 327680
        float bce = 0.f, inter = 0.f, ps = 0.f, ts = 0.f;
#pragma unroll
        for (int k = 0; k < 4; k++) {
            int i = base + k * stride;           // only k==3 can go OOB
            if (i < n4) {
                float4 pv = p4[i], tv = t4[i];
                {
                    float pp = pv.x, tt = tv.x;
                    bce -= tt * __logf(pp) + (1.f - tt) * __logf(1.f - pp);
                    inter += pp * tt; ps += pp; ts += tt;
                }
                {
                    float pp = pv.y, tt = tv.y;
                    bce -= tt * __logf(pp) + (1.f - tt) * __logf(1.f - pp);
                    inter += pp * tt; ps += pp; ts += tt;
                }
                {
                    float pp = pv.z, tt = tv.z;
                    bce -= tt * __logf(pp) + (1.f - tt) * __logf(1.f - pp);
                    inter += pp * tt; ps += pp; ts += tt;
                }
                {
                    float pp = pv.w, tt = tv.w;
                    bce -= tt * __logf(pp) + (1.f - tt) * __logf(1.f - pp);
                    inter += pp * tt; ps += pp; ts += tt;
                }
            }
        }
        bce = wave_sum(bce); inter = wave_sum(inter);
        ps  = wave_sum(ps);  ts    = wave_sum(ts);
        if (lane == 0) { sm[wid][0] = bce; sm[wid][1] = inter; sm[wid][2] = ps; sm[wid][3] = ts; }
        __syncthreads();
        if (tid == 0) {
            float a = 0, b = 0, c = 0, d = 0;
#pragma unroll
            for (int i2 = 0; i2 < 5; i2++) { a += sm[i2][0]; b += sm[i2][1]; c += sm[i2][2]; d += sm[i2][3]; }
            partials[blockIdx.x] = make_float4(a, b, c, d);
        }
    } else {
        // ---- box + confidence loss, one block per batch ----
        const int b = blockIdx.x - TR_BLOCKS;
        const int m = tid / NPTS;
        const int j = tid % NPTS;

        const float* tb = tboxes + (b * NM + m) * 5;
        float tconf = tb[0];
        float nx1 = fminf(fmaxf(tb[1] * (1.0f / NW), 0.f), 1.f);
        float ny1 = fminf(fmaxf(tb[2] * (1.0f / NH), 0.f), 1.f);
        float nx2 = fminf(fmaxf(tb[3] * (1.0f / NW), 0.f), 1.f);
        float ny2 = fminf(fmaxf(tb[4] * (1.0f / NH), 0.f), 1.f);
        int x1p = min(max((int)(nx1 * (float)NW), 0), NW - 1);
        int y1p = min(max((int)(ny1 * (float)NH), 0), NH - 1);
        int x2p = min(max((int)(nx2 * (float)NW), 0), NW - 1);
        int y2p = min(max((int)(ny2 * (float)NH), 0), NH - 1);
        int cy = (y1p + y2p) >> 1;
        int cx = (x1p + x2p) >> 1;

        int yy, xx;
        switch (j) {
            case 0: yy = cy;  xx = cx;  break;
            case 1: yy = y1p; xx = x1p; break;
            case 2: yy = y1p; xx = x2p; break;
            case 3: yy = y2p; xx = x1p; break;
            default: yy = y2p; xx = x2p; break;
        }
        int off = yy * NW + xx;
        const float* bbp = bbox + (size_t)b * 4 * HW;
        float p0 = bbp[off];
        float p1 = bbp[HW + off];
        float p2 = bbp[2 * HW + off];
        float p3 = bbp[3 * HW + off];
        float cp = confidence[(size_t)b * HW + off];

        float px1 = fminf(fmaxf(p0, 0.00f), 0.99f);
        float py1 = fminf(fmaxf(p1, 0.00f), 0.99f);
        float px2 = fminf(fmaxf(p2, 0.01f), 1.00f);
        float py2 = fminf(fmaxf(p3, 0.01f), 1.00f);
        float cx1 = fminf(px1, px2), cx2 = fmaxf(px1, px2);
        float cy1 = fminf(py1, py2), cy2 = fmaxf(py1, py2);

        float pa = (cx2 - cx1) * (cy2 - cy1);
        float ta = (nx2 - nx1) * (ny2 - ny1);
        float ix1 = fmaxf(cx1, nx1), iy1 = fmaxf(cy1, ny1);
        float ix2 = fminf(cx2, nx2), iy2 = fminf(cy2, ny2);
        float inter = fmaxf(ix2 - ix1, 0.f) * fmaxf(iy2 - iy1, 0.f);
        float uni = pa + ta - inter;
        float iou = inter / (uni + 1e-6f);
        float ex1 = fminf(cx1, nx1), ey1 = fminf(cy1, ny1);
        float ex2 = fmaxf(cx2, nx2), ey2 = fmaxf(cy2, ny2);
        float enc = (ex2 - ex1) * (ey2 - ey1);
        float giou = iou - (enc - uni) / (enc + 1e-6f);

        float iou_pt  = -logf(iou + 1e-6f);
        float giou_pt = 1.f - giou;

        float l1 = 0.f;
        {
            float d;
            d = fabsf(cx1 - nx1); l1 += (d < 1.f) ? 0.5f * d * d : d - 0.5f;
            d = fabsf(cy1 - ny1); l1 += (d < 1.f) ? 0.5f * d * d : d - 0.5f;
            d = fabsf(cx2 - nx2); l1 += (d < 1.f) ? 0.5f * d * d : d - 0.5f;
            d = fabsf(cy2 - ny2); l1 += (d < 1.f) ? 0.5f * d * d : d - 0.5f;
        }
        l1 *= 0.25f;

        float bcec = -(tconf * logf(cp) + (1.f - tconf) * logf(1.f - cp));

        float mk = (float)bmask[b * NM + m];

        float s_mask = mk;
        float s_iou  = iou_pt  * mk;
        float s_l1   = l1      * mk;
        float s_giou = giou_pt * mk;
        float s_conf = bcec    * mk;

        s_mask = wave_sum(s_mask); s_iou = wave_sum(s_iou); s_l1 = wave_sum(s_l1);
        s_giou = wave_sum(s_giou); s_conf = wave_sum(s_conf);
        if (lane == 0) {
            sm[wid][0] = s_mask; sm[wid][1] = s_iou; sm[wid][2] = s_l1;
            sm[wid][3] = s_giou; sm[wid][4] = s_conf;
        }
        __syncthreads();
        if (tid == 0) {
            float msum = 0, isum = 0, lsum = 0, gsum = 0, csum = 0;
#pragma unroll
            for (int w2 = 0; w2 < 5; w2++) {
                msum += sm[w2][0]; isum += sm[w2][1]; lsum += sm[w2][2];
                gsum += sm[w2][3]; csum += sm[w2][4];
            }
            float cnt = fmaxf(msum, 1.f);
            float combined = 0.5f * (isum / cnt) + 0.3f * (lsum / cnt) + 0.2f * (gsum / cnt);
            float conf_ps  = csum / cnt;
            float valid = (msum > 0.f) ? 1.f : 0.f;
            ws[b]      = combined * valid;   // distinct slots — no atomics
            ws[16 + b] = conf_ps * valid;
            ws[32 + b] = valid;
        }
    }
}

// ---------------- Kernel 2: fused final reduce + output ----------------
__global__ __launch_bounds__(256) void final_kernel(
        const float4* __restrict__ partials, const float* __restrict__ ws,
        float* __restrict__ out) {
    float a = 0.f, b = 0.f, c = 0.f, d = 0.f;
#pragma unroll
    for (int k = 0; k < TR_BLOCKS / 256; k++) {
        float4 v = partials[threadIdx.x + k * 256];
        a += v.x; b += v.y; c += v.z; d += v.w;
    }
    int lane = threadIdx.x & 63, wid = threadIdx.x >> 6;
    a = wave_sum(a); b = wave_sum(b); c = wave_sum(c); d = wave_sum(d);
    __shared__ float sm[4][4];
    if (lane == 0) { sm[wid][0] = a; sm[wid][1] = b; sm[wid][2] = c; sm[wid][3] = d; }
    __syncthreads();
    if (threadIdx.x == 0) {
        float s0 = 0, s1 = 0, s2 = 0, s3 = 0;
#pragma unroll
        for (int i2 = 0; i2 < 4; i2++) { s0 += sm[i2][0]; s1 += sm[i2][1]; s2 += sm[i2][2]; s3 += sm[i2][3]; }
        float bce_mean  = s0 / (float)BHW;
        float dice      = (2.f * s1 + 1e-5f) / (s2 + s3 + 1e-5f);
        float text_loss = 0.5f * bce_mean + 0.5f * (1.f - dice);
        float box_sum = 0.f, conf_sum = 0.f, valid_sum = 0.f;
#pragma unroll
        for (int bb = 0; bb < NB; bb++) {
            box_sum   += ws[bb];
            conf_sum  += ws[16 + bb];
            valid_sum += ws[32 + bb];
        }
        float nvalid = fmaxf(valid_sum, 1.f);
        out[0] = 1.0f * text_loss + 20.0f * (box_sum / nvalid) + 0.5f * (conf_sum / nvalid);
    }
}

extern "C" void kernel_launch(void* const* d_in, const int* in_sizes, int n_in,
                              void* d_out, int out_size, void* d_ws, size_t ws_size,
                              hipStream_t stream) {
    const float* text_map        = (const float*)d_in[0];
    const float* confidence      = (const float*)d_in[1];
    const float* bbox_coords     = (const float*)d_in[2];
    const float* target_text_map = (const float*)d_in[3];
    const float* target_boxes    = (const float*)d_in[4];
    const int*   box_mask        = (const int*)d_in[5];
    float* out = (float*)d_out;
    float* ws  = (float*)d_ws;

    float4* partials = (float4*)((char*)d_ws + 256);   // 1024 * 16 B = 16 KiB

    // Blocks 0..1023: text partials (33.6 MB read). Blocks 1024..1039: box/conf.
    // NOTE R5 post-mortem: hipLaunchCooperativeKernel silently fails to execute
    // in this harness — do NOT use grid.sync() fusion here.
    fused_main_kernel<<<TR_BLOCKS + NB, THREADS, 0, stream>>>(
        text_map, target_text_map, confidence, bbox_coords,
        target_boxes, box_mask, partials, ws);

    final_kernel<<<1, 256, 0, stream>>>(partials, ws, out);
}